// Round 4
// baseline (62.169 us; speedup 1.0000x reference)
//
#include <hip/hip_runtime.h>

// FractalEmbedding: cs[M,2] -> 8 Julia iters -> feats[M,16]
//                   out[M,D] = feats @ W^T * scale   (W is [D,16] row-major)
// M = 32768, D = 2048, fp32 out = 256 MiB -> write-BW-bound (~38us @ 7 TB/s).
//
// R4: MFMA rewrite. Per wave: 16 rows x 128 cols per row-tile step.
//  - Julia once per lane (4x redundancy, not 512x), packed into B-frag.
//  - dot = mfma_f32_16x16x32_bf16 with K padded 16->32 (zeros), 3-term
//    hi/lo bf16 split (Wh*Fh + Wh*Fl + Wl*Fh) for fp32-grade accuracy.
//  - C-layout: lane holds 4 consecutive d for one row -> one f32x4 store.
//  - 12x less issue per byte; 8 independent MFMA+store pairs per tile = ILP.

#define STEPS 8
#define KF 16
#define DDIM 2048
#define BLOCK 256
#define WAVES 4
#define NCT 8                               // 16-col tiles per wave
#define COLS_PER_WAVE (NCT * 16)            // 128
#define CGROUPS (DDIM / COLS_PER_WAVE)      // 16
#define RT_PER_WAVE 4                       // 16-row tiles per wave
#define ROWS_PER_BLOCK (WAVES * RT_PER_WAVE * 16)  // 256

static_assert(CGROUPS == 16, "blockIdx decomposition assumes 16 col groups");

typedef float f32x2  __attribute__((ext_vector_type(2)));
typedef float f32x4  __attribute__((ext_vector_type(4)));
typedef short bf16x8 __attribute__((ext_vector_type(8)));

static __device__ inline unsigned short bf16_rne(float x) {
    unsigned u = __float_as_uint(x);
    u += 0x7FFFu + ((u >> 16) & 1u);
    return (unsigned short)(u >> 16);
}
static __device__ inline float bf16_f32(unsigned short h) {
    return __uint_as_float(((unsigned)h) << 16);
}

__global__ __launch_bounds__(BLOCK) void fractal_embed_mfma(
    const float* __restrict__ cs,     // [M,2]
    const float* __restrict__ W,      // [D,16]
    const float* __restrict__ scale,  // [1]
    float* __restrict__ out)          // [M,D]
{
    const int tid  = threadIdx.x;
    const int lane = tid & 63;
    const int wv   = tid >> 6;
    const int r15  = lane & 15;       // token-row within tile / W-row within tile
    const int g    = lane >> 4;       // k-group (8 consecutive k per group)

    const int cg    = blockIdx.x & (CGROUPS - 1);
    const int rg    = blockIdx.x >> 4;
    const int dwave = cg * COLS_PER_WAVE;
    const int rt0   = (rg * WAVES + wv) * RT_PER_WAVE;

    // Prefetch all this wave's cs pairs up-front (independent loads in flight
    // under the W-frag setup).
    f32x2 cpre[RT_PER_WAVE];
#pragma unroll
    for (int t = 0; t < RT_PER_WAVE; ++t)
        cpre[t] = reinterpret_cast<const f32x2*>(cs)[(rt0 + t) * 16 + r15];

    const float s = scale[0];

    // A-frags: W rows for this wave's 128 cols, scale folded in, hi/lo split.
    // A[m][k]: lane = m + 16*(k>>3), elem e -> k = g*8+e. k>=16 is zero pad.
    bf16x8 wh[NCT], wl[NCT];
#pragma unroll
    for (int ct = 0; ct < NCT; ++ct) {
        const int d = dwave + ct * 16 + r15;
        f32x4 a0 = {0.f, 0.f, 0.f, 0.f}, a1 = {0.f, 0.f, 0.f, 0.f};
        if (g < 2) {  // g0: k 0..7, g1: k 8..15, g2/g3: zero pad
            const f32x4* wp = reinterpret_cast<const f32x4*>(W + (size_t)d * KF + g * 8);
            a0 = wp[0];
            a1 = wp[1];
        }
        float v[8] = {a0.x * s, a0.y * s, a0.z * s, a0.w * s,
                      a1.x * s, a1.y * s, a1.z * s, a1.w * s};
#pragma unroll
        for (int e = 0; e < 8; ++e) {
            const unsigned short hh = bf16_rne(v[e]);
            const float lo = v[e] - bf16_f32(hh);
            wh[ct][e] = (short)hh;
            wl[ct][e] = (short)bf16_rne(lo);
        }
    }

#pragma unroll
    for (int t = 0; t < RT_PER_WAVE; ++t) {
        const int rowbase = (rt0 + t) * 16;
        const float cr = cpre[t].x, ci = cpre[t].y;

        // Julia for this lane's token row (row = rowbase + r15).
        float fk[2 * STEPS];
        float zr = 0.f, zi = 0.f;
#pragma unroll
        for (int st = 0; st < STEPS; ++st) {
            const float nzr = fmaf(zr, zr, fmaf(-zi, zi, cr));
            const float nzi = fmaf(zr + zr, zi, ci);
            zr = nzr; zi = nzi;
            fk[2 * st] = zr;
            fk[2 * st + 1] = zi;
        }

        // B-frag: B[k][n]: lane = n + 16*(k>>3), n = token row, k = g*8+e.
        bf16x8 bh, bl;
#pragma unroll
        for (int e = 0; e < 8; ++e) {
            const float v = (g == 0) ? fk[e] : ((g == 1) ? fk[8 + e] : 0.0f);
            const unsigned short hh = bf16_rne(v);
            const float lo = v - bf16_f32(hh);
            bh[e] = (short)hh;
            bl[e] = (short)bf16_rne(lo);
        }

        // C/D: lane holds D[m = g*4+reg][n = r15] -> 4 consecutive d, one row.
        float* op = out + (size_t)(rowbase + r15) * DDIM + dwave + g * 4;
#pragma unroll
        for (int ct = 0; ct < NCT; ++ct) {
            f32x4 acc = {0.f, 0.f, 0.f, 0.f};
            acc = __builtin_amdgcn_mfma_f32_16x16x32_bf16(wh[ct], bh, acc, 0, 0, 0);
            acc = __builtin_amdgcn_mfma_f32_16x16x32_bf16(wh[ct], bl, acc, 0, 0, 0);
            acc = __builtin_amdgcn_mfma_f32_16x16x32_bf16(wl[ct], bh, acc, 0, 0, 0);
            reinterpret_cast<f32x4*>(op + ct * 16)[0] = acc;
        }
    }
}

extern "C" void kernel_launch(void* const* d_in, const int* in_sizes, int n_in,
                              void* d_out, int out_size, void* d_ws, size_t ws_size,
                              hipStream_t stream) {
    // d_in[0] = token_ids (int64, unused — cs precomputed host-side)
    // d_in[1] = cs [B,L,2] f32; d_in[2] = W [D,16] f32; d_in[3] = scale [1] f32
    const float* cs    = (const float*)d_in[1];
    const float* W     = (const float*)d_in[2];
    const float* scale = (const float*)d_in[3];
    float* out         = (float*)d_out;

    const int M = in_sizes[0];                     // B*L = 32768 rows
    const int rowgroups = M / ROWS_PER_BLOCK;      // 128
    const int grid = CGROUPS * rowgroups;          // 2048 blocks
    fractal_embed_mfma<<<grid, BLOCK, 0, stream>>>(cs, W, scale, out);
}

// Round 5
// 56.998 us; speedup vs baseline: 1.0907x; 1.0907x over previous
//
#include <hip/hip_runtime.h>

// FractalEmbedding: cs[M,2] -> 8 Julia iters -> feats[M,16]
//                   out[M,D] = feats @ W^T * scale   (W is [D,16] row-major)
// M = 32768, D = 2048, fp32 out = 256 MiB -> write-BW-bound (fill = 7 TB/s
// => ~38us floor).
//
// R5: fill-mimicking store stream. Each block owns a fully CONTIGUOUS 256 KB
// output slab (32 rows x all 2048 cols), written row-major:
//  - thread t owns cols {4t..4t+3} and {1024+4t..4t+3+1024} -> each wave
//    store instr is a dense 1 KB contiguous segment (lanes 16 B apart).
//  - W rows for those 8 cols in registers (128 VGPR), scale folded in.
//  - Julia wave-uniform per row from LDS-staged cs; pk-fma dot.
// Theory: R2-R4 proved compute structure is irrelevant (59-62us for three
// different kernels); the gap to fill's 7 TB/s is per-block write contiguity.

#define STEPS 8
#define KF 16
#define DDIM 2048
#define BLOCK 256
#define CPT 8                 // columns per thread: two dense 4-col groups
#define ROWS_PER_BLK 32

typedef float f32x2 __attribute__((ext_vector_type(2)));
typedef float f32x4 __attribute__((ext_vector_type(4)));

__global__ __launch_bounds__(BLOCK, 2) void fractal_embed_kernel(
    const float* __restrict__ cs,     // [M,2] interleaved (cr, ci)
    const float* __restrict__ W,      // [D,16] row-major
    const float* __restrict__ scale,  // [1]
    float* __restrict__ out)          // [M,D]
{
    const int tid  = threadIdx.x;
    const int row0 = blockIdx.x * ROWS_PER_BLK;
    const int ca   = tid * 4;          // cols    0..1023 across the block
    const int cb   = 1024 + tid * 4;   // cols 1024..2047 across the block

    // Stage this block's 32 (cr,ci) pairs into LDS: one coalesced 256 B load.
    __shared__ float s_cs[2 * ROWS_PER_BLK];
    if (tid < 2 * ROWS_PER_BLK)
        s_cs[tid] = cs[(size_t)row0 * 2 + tid];

    const float s = scale[0];

    // W rows for this thread's 8 columns, scale folded in. 128 VGPRs.
    f32x2 w2[CPT][KF / 2];
#pragma unroll
    for (int r = 0; r < CPT; ++r) {
        const int d = (r < 4) ? (ca + r) : (cb + (r - 4));
        const f32x2* wp = reinterpret_cast<const f32x2*>(W + (size_t)d * KF);
#pragma unroll
        for (int q = 0; q < KF / 2; ++q) {
            f32x2 v = wp[q];
            v.x *= s; v.y *= s;
            w2[r][q] = v;
        }
    }
    __syncthreads();

#pragma unroll 2
    for (int rr = 0; rr < ROWS_PER_BLK; ++rr) {
        const int row = row0 + rr;
        const float cr = s_cs[2 * rr];       // wave-uniform broadcast reads
        const float ci = s_cs[2 * rr + 1];

        // Julia iteration z <- z^2 + c from z=0; f2[st] = (zr, zi).
        f32x2 f2[STEPS];
        float zr = 0.0f, zi = 0.0f;
#pragma unroll
        for (int st = 0; st < STEPS; ++st) {
            const float nzr = fmaf(zr, zr, fmaf(-zi, zi, cr));
            const float nzi = fmaf(zr + zr, zi, ci);
            zr = nzr; zi = nzi;
            f2[st].x = zr;
            f2[st].y = zi;
        }

        // 8 dot products (length 16) via pk-fma against register W.
        f32x4 oa, ob;
#pragma unroll
        for (int r = 0; r < CPT; ++r) {
            f32x2 a2 = {0.0f, 0.0f};
#pragma unroll
            for (int q = 0; q < KF / 2; ++q)
                a2 = __builtin_elementwise_fma(f2[q], w2[r][q], a2);
            const float v = a2.x + a2.y;
            if (r < 4) oa[r] = v;
            else       ob[r - 4] = v;
        }

        // Two dense 1 KB-per-wave stores; block walks a 256 KB slab row-major.
        float* rowp = out + (size_t)row * DDIM;
        reinterpret_cast<f32x4*>(rowp + ca)[0] = oa;
        reinterpret_cast<f32x4*>(rowp + cb)[0] = ob;
    }
}

extern "C" void kernel_launch(void* const* d_in, const int* in_sizes, int n_in,
                              void* d_out, int out_size, void* d_ws, size_t ws_size,
                              hipStream_t stream) {
    // d_in[0] = token_ids (int64, unused — cs precomputed host-side)
    // d_in[1] = cs [B,L,2] f32; d_in[2] = W [D,16] f32; d_in[3] = scale [1] f32
    const float* cs    = (const float*)d_in[1];
    const float* W     = (const float*)d_in[2];
    const float* scale = (const float*)d_in[3];
    float* out         = (float*)d_out;

    const int M = in_sizes[0];                 // B*L = 32768 rows
    const int grid = M / ROWS_PER_BLK;         // 1024 blocks, 256 KB slab each
    fractal_embed_kernel<<<grid, BLOCK, 0, stream>>>(cs, W, scale, out);
}